// Round 2
// baseline (275.689 us; speedup 1.0000x reference)
//
#include <hip/hip_runtime.h>
#include <hip/hip_bf16.h>
#include <math.h>

#define D 1024

constexpr float TEMPORAL_DECAY = 0.1f;
constexpr float REL_TERM      = 0.1f;   // RELEVANCE_BOOST * RELEVANCE_SCORE = 0.2*0.5
constexpr float SIM_THRESHOLD = 0.7f;
constexpr float COS_EPS       = 1e-8f;
constexpr float LN_EPS        = 1e-5f;

// ---------------------------------------------------------------------------
// Kernel 1/2: Y[b][j] = act(sum_d X[b][d] * W[d][j] + bias[j]), B = 4 rows.
// W is read exactly once across the grid (coalesced over j); X staged in LDS.
// grid = 32 blocks, block = 256 (32 j-lanes x 8 d-groups of 128).
// ---------------------------------------------------------------------------
template <bool RELU>
__global__ __launch_bounds__(256) void small_gemm(const float* __restrict__ X,
                                                  const float* __restrict__ W,
                                                  const float* __restrict__ bias,
                                                  float* __restrict__ Y) {
    __shared__ float xs[4 * D];
    __shared__ float red[8][4][32];
    const int tid = threadIdx.x;

    // cooperative load of X (16 KB) as float4
    const float4* X4  = (const float4*)X;
    float4*       xs4 = (float4*)xs;
    for (int i = tid; i < D; i += 256) xs4[i] = X4[i];
    __syncthreads();

    const int jj = tid & 31;
    const int dg = tid >> 5;
    const int j  = blockIdx.x * 32 + jj;

    float a0 = 0.f, a1 = 0.f, a2 = 0.f, a3 = 0.f;
    const int d0 = dg * 128;
    for (int d = d0; d < d0 + 128; ++d) {
        float w = W[d * D + j];
        a0 = fmaf(xs[0 * D + d], w, a0);
        a1 = fmaf(xs[1 * D + d], w, a1);
        a2 = fmaf(xs[2 * D + d], w, a2);
        a3 = fmaf(xs[3 * D + d], w, a3);
    }
    red[dg][0][jj] = a0;
    red[dg][1][jj] = a1;
    red[dg][2][jj] = a2;
    red[dg][3][jj] = a3;
    __syncthreads();

    if (tid < 128) {
        const int b  = tid >> 5;
        const int jl = tid & 31;
        float s = 0.f;
#pragma unroll
        for (int g = 0; g < 8; ++g) s += red[g][b][jl];
        s += bias[blockIdx.x * 32 + jl];
        if (RELU) s = fmaxf(s, 0.f);
        Y[b * D + blockIdx.x * 32 + jl] = s;
    }
}

// ---------------------------------------------------------------------------
// Kernel 3: per context row: LayerNorm then cosine pre-normalization.
// grid = 4 (one block per row), block = 256, each thread owns one float4.
// ---------------------------------------------------------------------------
__global__ __launch_bounds__(256) void ln_cosnorm(const float* __restrict__ H,
                                                  const float* __restrict__ gamma,
                                                  const float* __restrict__ beta,
                                                  float* __restrict__ out) {
    const int r   = blockIdx.x;
    const int tid = threadIdx.x;
    const int lane = tid & 63;
    const int wid  = tid >> 6;

    const float4 v = ((const float4*)(H + r * D))[tid];
    float s  = v.x + v.y + v.z + v.w;
    float ss = v.x * v.x + v.y * v.y + v.z * v.z + v.w * v.w;

    __shared__ float rs_[2][4];
#pragma unroll
    for (int off = 32; off; off >>= 1) {
        s  += __shfl_xor(s, off, 64);
        ss += __shfl_xor(ss, off, 64);
    }
    if (lane == 0) { rs_[0][wid] = s; rs_[1][wid] = ss; }
    __syncthreads();
    s  = rs_[0][0] + rs_[0][1] + rs_[0][2] + rs_[0][3];
    ss = rs_[1][0] + rs_[1][1] + rs_[1][2] + rs_[1][3];

    const float mu   = s * (1.f / D);
    const float var  = ss * (1.f / D) - mu * mu;
    const float rstd = rsqrtf(var + LN_EPS);

    const float4 g  = ((const float4*)gamma)[tid];
    const float4 bb = ((const float4*)beta)[tid];
    float4 y;
    y.x = (v.x - mu) * rstd * g.x + bb.x;
    y.y = (v.y - mu) * rstd * g.y + bb.y;
    y.z = (v.z - mu) * rstd * g.z + bb.z;
    y.w = (v.w - mu) * rstd * g.w + bb.w;

    float nsq = y.x * y.x + y.y * y.y + y.z * y.z + y.w * y.w;
#pragma unroll
    for (int off = 32; off; off >>= 1) nsq += __shfl_xor(nsq, off, 64);
    __shared__ float rn[4];
    if (lane == 0) rn[wid] = nsq;
    __syncthreads();
    nsq = rn[0] + rn[1] + rn[2] + rn[3];

    const float inv = 1.f / fmaxf(sqrtf(nsq), COS_EPS);
    float4 o;
    o.x = y.x * inv; o.y = y.y * inv; o.z = y.z * inv; o.w = y.w * inv;
    ((float4*)(out + r * D))[tid] = o;
}

// ---------------------------------------------------------------------------
// Kernel 4 (the streaming pass): one wave per episode row, grid-stride.
// Per row: 4x float4 loads/lane (4 KB total), 5 wave reductions,
// lanes 0..3 apply cosine denom + temporal weight + threshold and store.
// ---------------------------------------------------------------------------
__global__ __launch_bounds__(256) void score_kernel(const float* __restrict__ ep,
                                                    const float* __restrict__ elapsed,
                                                    const float* __restrict__ ctxn,
                                                    float* __restrict__ out, int N) {
    const int lane = threadIdx.x & 63;
    const int wave = (blockIdx.x * 256 + threadIdx.x) >> 6;
    const int nw   = (gridDim.x * 256) >> 6;

    // preload the 4 normalized context rows: lane's 16 d's = lane*4 + k*256
    const float4* c4 = (const float4*)ctxn;
    float4 c[4][4];
#pragma unroll
    for (int b = 0; b < 4; ++b)
#pragma unroll
        for (int k = 0; k < 4; ++k) c[b][k] = c4[b * 256 + k * 64 + lane];

    for (int n = wave; n < N; n += nw) {
        const float4* e4 = (const float4*)(ep + (size_t)n * D);
        float acc[5] = {0.f, 0.f, 0.f, 0.f, 0.f};
#pragma unroll
        for (int k = 0; k < 4; ++k) {
            const float4 e = e4[k * 64 + lane];
            acc[4] = fmaf(e.x, e.x, fmaf(e.y, e.y, fmaf(e.z, e.z, fmaf(e.w, e.w, acc[4]))));
#pragma unroll
            for (int b = 0; b < 4; ++b) {
                acc[b] = fmaf(e.x, c[b][k].x,
                         fmaf(e.y, c[b][k].y,
                         fmaf(e.z, c[b][k].z,
                         fmaf(e.w, c[b][k].w, acc[b]))));
            }
        }
#pragma unroll
        for (int off = 32; off; off >>= 1)
#pragma unroll
            for (int i = 0; i < 5; ++i) acc[i] += __shfl_xor(acc[i], off, 64);

        if (lane < 4) {
            const float inv = 1.f / fmaxf(sqrtf(acc[4]), COS_EPS);
            const float w   = expf(-TEMPORAL_DECAY * elapsed[n]) + REL_TERM;
            const float sc  = acc[lane] * inv * w;
            out[(size_t)lane * N + n] = (sc > SIM_THRESHOLD) ? sc : 0.f;
        }
    }
}

// ---------------------------------------------------------------------------
extern "C" void kernel_launch(void* const* d_in, const int* in_sizes, int n_in,
                              void* d_out, int out_size, void* d_ws, size_t ws_size,
                              hipStream_t stream) {
    const float* ctx = (const float*)d_in[0];
    const float* ep  = (const float*)d_in[1];
    const float* el  = (const float*)d_in[2];
    const float* W1  = (const float*)d_in[3];
    const float* b1  = (const float*)d_in[4];
    const float* W2  = (const float*)d_in[5];
    const float* b2  = (const float*)d_in[6];
    const float* gg  = (const float*)d_in[7];
    const float* bb  = (const float*)d_in[8];
    float* out = (float*)d_out;
    const int N = in_sizes[2];

    float* h1 = (float*)d_ws;       // [4,1024]
    float* h2 = h1 + 4 * D;         // [4,1024]
    float* cn = h2 + 4 * D;         // [4,1024] normalized context

    small_gemm<true><<<32, 256, 0, stream>>>(ctx, W1, b1, h1);
    small_gemm<false><<<32, 256, 0, stream>>>(h1, W2, b2, h2);
    ln_cosnorm<<<4, 256, 0, stream>>>(h2, gg, bb, cn);
    score_kernel<<<2048, 256, 0, stream>>>(ep, el, cn, out, N);
}

// Round 3
// 167.982 us; speedup vs baseline: 1.6412x; 1.6412x over previous
//
#include <hip/hip_runtime.h>
#include <hip/hip_bf16.h>
#include <math.h>

#define D 1024

using vf4 = __attribute__((ext_vector_type(4))) float;

constexpr float TEMPORAL_DECAY = 0.1f;
constexpr float REL_TERM      = 0.1f;   // RELEVANCE_BOOST * RELEVANCE_SCORE
constexpr float SIM_THRESHOLD = 0.7f;
constexpr float COS_EPS       = 1e-8f;
constexpr float LN_EPS        = 1e-5f;

// ---------------------------------------------------------------------------
// K1/K3: partial GEMM. partial[s][b][j] = sum_{d in slice s} X[b][d] * W[d][j]
// grid = 128 (slices of 8 d-rows), block = 256. W reads: 64 lanes x float4 =
// 1 KB/instr, W read exactly once. X[b][d] is wave-uniform -> s_load.
// ---------------------------------------------------------------------------
__global__ __launch_bounds__(256) void gemm_partial(const float* __restrict__ X,
                                                    const float* __restrict__ W,
                                                    float* __restrict__ partial) {
    const int s = blockIdx.x, t = threadIdx.x;
    const vf4* W4 = (const vf4*)W;
    vf4 a0 = {0.f, 0.f, 0.f, 0.f}, a1 = a0, a2 = a0, a3 = a0;
#pragma unroll
    for (int i = 0; i < 8; ++i) {
        const int d = s * 8 + i;
        const vf4 w = W4[d * 256 + t];
        a0 += X[0 * D + d] * w;
        a1 += X[1 * D + d] * w;
        a2 += X[2 * D + d] * w;
        a3 += X[3 * D + d] * w;
    }
    vf4* P4 = (vf4*)partial;
    P4[(s * 4 + 0) * 256 + t] = a0;
    P4[(s * 4 + 1) * 256 + t] = a1;
    P4[(s * 4 + 2) * 256 + t] = a2;
    P4[(s * 4 + 3) * 256 + t] = a3;
}

// ---------------------------------------------------------------------------
// K2: reduce 128 partial slices + bias + ReLU -> h1[4][1024].
// grid = 16, block = 256, one output scalar per thread (coalesced over j).
// ---------------------------------------------------------------------------
__global__ __launch_bounds__(256) void reduce_bias_relu(const float* __restrict__ partial,
                                                        const float* __restrict__ bias,
                                                        float* __restrict__ Y) {
    const int o = blockIdx.x * 256 + threadIdx.x;   // 0..4095
    const int b = o >> 10, j = o & 1023;
    float s = 0.f;
#pragma unroll 8
    for (int sl = 0; sl < 128; ++sl) s += partial[(sl * 4 + b) * D + j];
    s += bias[j];
    Y[o] = fmaxf(s, 0.f);
}

// ---------------------------------------------------------------------------
// K4: reduce partial2 + bias, then LayerNorm, then cosine pre-normalization.
// grid = 4 (one block per context row), block = 256, one float4 per thread.
// ---------------------------------------------------------------------------
__global__ __launch_bounds__(256) void reduce_ln_cosnorm(const float* __restrict__ partial,
                                                         const float* __restrict__ bias,
                                                         const float* __restrict__ gamma,
                                                         const float* __restrict__ beta,
                                                         float* __restrict__ out) {
    const int b = blockIdx.x, t = threadIdx.x;
    const int lane = t & 63, wid = t >> 6;

    const vf4* P4 = (const vf4*)partial;
    vf4 acc = {0.f, 0.f, 0.f, 0.f};
#pragma unroll 8
    for (int sl = 0; sl < 128; ++sl) acc += P4[(sl * 4 + b) * 256 + t];
    acc += ((const vf4*)bias)[t];

    float s  = acc[0] + acc[1] + acc[2] + acc[3];
    float ss = acc[0] * acc[0] + acc[1] * acc[1] + acc[2] * acc[2] + acc[3] * acc[3];

    __shared__ float rs_[2][4];
#pragma unroll
    for (int off = 32; off; off >>= 1) {
        s  += __shfl_xor(s, off, 64);
        ss += __shfl_xor(ss, off, 64);
    }
    if (lane == 0) { rs_[0][wid] = s; rs_[1][wid] = ss; }
    __syncthreads();
    s  = rs_[0][0] + rs_[0][1] + rs_[0][2] + rs_[0][3];
    ss = rs_[1][0] + rs_[1][1] + rs_[1][2] + rs_[1][3];

    const float mu   = s * (1.f / D);
    const float var  = ss * (1.f / D) - mu * mu;
    const float rstd = rsqrtf(var + LN_EPS);

    const vf4 g  = ((const vf4*)gamma)[t];
    const vf4 bb = ((const vf4*)beta)[t];
    vf4 y;
#pragma unroll
    for (int i = 0; i < 4; ++i) y[i] = (acc[i] - mu) * rstd * g[i] + bb[i];

    float nsq = y[0] * y[0] + y[1] * y[1] + y[2] * y[2] + y[3] * y[3];
#pragma unroll
    for (int off = 32; off; off >>= 1) nsq += __shfl_xor(nsq, off, 64);
    __shared__ float rn[4];
    if (lane == 0) rn[wid] = nsq;
    __syncthreads();
    nsq = rn[0] + rn[1] + rn[2] + rn[3];

    const float inv = 1.f / fmaxf(sqrtf(nsq), COS_EPS);
    vf4 o;
#pragma unroll
    for (int i = 0; i < 4; ++i) o[i] = y[i] * inv;
    ((vf4*)(out + b * D))[t] = o;
}

// ---------------------------------------------------------------------------
// K5 (the streaming pass): one wave per episode row, 2 rows per iteration.
// 8 independent nontemporal float4 loads in flight, then a packed butterfly:
// level-32 merges row-pair accs (lanes<32 keep row-n partials, lanes>=32 keep
// row-n2 partials), then 5 more levels on the merged regs.
// ---------------------------------------------------------------------------
__global__ __launch_bounds__(256) void score_kernel(const float* __restrict__ ep,
                                                    const float* __restrict__ elapsed,
                                                    const float* __restrict__ ctxn,
                                                    float* __restrict__ out, int N) {
    const int lane = threadIdx.x & 63;
    const int wave = (blockIdx.x * 256 + threadIdx.x) >> 6;
    const int nw   = (gridDim.x * 256) >> 6;

    // preload the 4 normalized context rows (16 floats/lane/row)
    const vf4* c4 = (const vf4*)ctxn;
    vf4 c[4][4];
#pragma unroll
    for (int b = 0; b < 4; ++b)
#pragma unroll
        for (int k = 0; k < 4; ++k) c[b][k] = c4[b * 256 + k * 64 + lane];

    for (int n = wave; n < N; n += 2 * nw) {
        const int  n2    = n + nw;
        const bool have2 = n2 < N;

        const vf4* eA = (const vf4*)(ep + (size_t)n * D);
        const vf4* eB = (const vf4*)(ep + (size_t)n2 * D);

        vf4 ea[4], eb[4];
#pragma unroll
        for (int k = 0; k < 4; ++k) ea[k] = __builtin_nontemporal_load(eA + k * 64 + lane);
        if (have2) {
#pragma unroll
            for (int k = 0; k < 4; ++k) eb[k] = __builtin_nontemporal_load(eB + k * 64 + lane);
        } else {
#pragma unroll
            for (int k = 0; k < 4; ++k) eb[k] = vf4{0.f, 0.f, 0.f, 0.f};
        }

        float a[5] = {0.f, 0.f, 0.f, 0.f, 0.f};
        float bacc[5] = {0.f, 0.f, 0.f, 0.f, 0.f};
#pragma unroll
        for (int k = 0; k < 4; ++k) {
#pragma unroll
            for (int i = 0; i < 4; ++i) {
                a[4]    = fmaf(ea[k][i], ea[k][i], a[4]);
                bacc[4] = fmaf(eb[k][i], eb[k][i], bacc[4]);
            }
#pragma unroll
            for (int b = 0; b < 4; ++b) {
#pragma unroll
                for (int i = 0; i < 4; ++i) {
                    a[b]    = fmaf(ea[k][i], c[b][k][i], a[b]);
                    bacc[b] = fmaf(eb[k][i], c[b][k][i], bacc[b]);
                }
            }
        }

        // packed reduction: level 32 merges the two rows, 5 levels finish.
        float m[5];
#pragma unroll
        for (int i = 0; i < 5; ++i) {
            const float t = __shfl_xor(a[i], 32, 64);
            const float u = __shfl_xor(bacc[i], 32, 64);
            m[i] = (lane < 32) ? (a[i] + t) : (bacc[i] + u);
        }
#pragma unroll
        for (int off = 16; off; off >>= 1)
#pragma unroll
            for (int i = 0; i < 5; ++i) m[i] += __shfl_xor(m[i], off, 64);

        // lanes 0..31 hold row-n sums, lanes 32..63 hold row-n2 sums
        const int  half = lane >> 5;
        const int  rown = half ? n2 : n;
        if ((lane & 31) < 4 && (half == 0 || have2)) {
            const int   bsel = lane & 3;
            const float sim  = bsel == 0 ? m[0] : bsel == 1 ? m[1] : bsel == 2 ? m[2] : m[3];
            const float inv  = 1.f / fmaxf(sqrtf(m[4]), COS_EPS);
            const float w    = expf(-TEMPORAL_DECAY * elapsed[rown]) + REL_TERM;
            const float sc   = sim * inv * w;
            out[(size_t)bsel * N + rown] = (sc > SIM_THRESHOLD) ? sc : 0.f;
        }
    }
}

// ---------------------------------------------------------------------------
extern "C" void kernel_launch(void* const* d_in, const int* in_sizes, int n_in,
                              void* d_out, int out_size, void* d_ws, size_t ws_size,
                              hipStream_t stream) {
    const float* ctx = (const float*)d_in[0];
    const float* ep  = (const float*)d_in[1];
    const float* el  = (const float*)d_in[2];
    const float* W1  = (const float*)d_in[3];
    const float* b1  = (const float*)d_in[4];
    const float* W2  = (const float*)d_in[5];
    const float* b2  = (const float*)d_in[6];
    const float* gg  = (const float*)d_in[7];
    const float* bb  = (const float*)d_in[8];
    float* out = (float*)d_out;
    const int N = in_sizes[2];

    float* p1 = (float*)d_ws;             // [128][4][1024] = 2 MB
    float* h1 = p1 + 128 * 4 * D;         // [4][1024]
    float* p2 = h1 + 4 * D;               // [128][4][1024] = 2 MB
    float* cn = p2 + 128 * 4 * D;         // [4][1024] normalized context

    gemm_partial<<<128, 256, 0, stream>>>(ctx, W1, p1);
    reduce_bias_relu<<<16, 256, 0, stream>>>(p1, b1, h1);
    gemm_partial<<<128, 256, 0, stream>>>(h1, W2, p2);
    reduce_ln_cosnorm<<<4, 256, 0, stream>>>(p2, b2, gg, bb, cn);
    score_kernel<<<2048, 256, 0, stream>>>(ep, el, cn, out, N);
}

// Round 4
// 160.141 us; speedup vs baseline: 1.7215x; 1.0490x over previous
//
#include <hip/hip_runtime.h>
#include <hip/hip_bf16.h>
#include <math.h>

#define D 1024

using vf4 = __attribute__((ext_vector_type(4))) float;

constexpr float TEMPORAL_DECAY = 0.1f;
constexpr float REL_TERM      = 0.1f;   // RELEVANCE_BOOST * RELEVANCE_SCORE
constexpr float SIM_THRESHOLD = 0.7f;
constexpr float COS_EPS       = 1e-8f;
constexpr float LN_EPS        = 1e-5f;

// ---------------------------------------------------------------------------
// K1: gemm1 split-K partial. p1[s][b][j] = sum_{d in 16-row slice s} X[b][d]*W1[d][j]
// grid = 64, block = 256. W1 read exactly once, coalesced vf4 over j.
// X[b][d] is wave-uniform -> scalar loads.
// ---------------------------------------------------------------------------
__global__ __launch_bounds__(256) void g1_partial(const float* __restrict__ X,
                                                  const float* __restrict__ W,
                                                  float* __restrict__ p1) {
    const int s = blockIdx.x, t = threadIdx.x;
    const vf4* W4 = (const vf4*)W;
    vf4 a0 = {0.f, 0.f, 0.f, 0.f}, a1 = a0, a2 = a0, a3 = a0;
#pragma unroll
    for (int i = 0; i < 16; ++i) {
        const int d = s * 16 + i;
        const vf4 w = W4[d * 256 + t];
        a0 += X[0 * D + d] * w;
        a1 += X[1 * D + d] * w;
        a2 += X[2 * D + d] * w;
        a3 += X[3 * D + d] * w;
    }
    vf4* P4 = (vf4*)p1;
    P4[(s * 4 + 0) * 256 + t] = a0;
    P4[(s * 4 + 1) * 256 + t] = a1;
    P4[(s * 4 + 2) * 256 + t] = a2;
    P4[(s * 4 + 3) * 256 + t] = a3;
}

// ---------------------------------------------------------------------------
// K2: fused [reduce p1 + bias + ReLU] -> hs (LDS) -> gemm2 split-K partial.
// grid = 32 (d-groups of 32 for gemm2), block = 256.
// Phase A: 8 groups of 32 lanes; group g = (b = g&3, half = g>>2) reduces 32
//          of the 64 p1 slices for this block's 32 h1 columns (coalesced).
// Phase B: p2[s][b][j] = sum_{i<32} hs[b][i] * W2[s*32+i][j].
// ---------------------------------------------------------------------------
__global__ __launch_bounds__(256) void g2_fused(const float* __restrict__ p1,
                                                const float* __restrict__ bias,
                                                const float* __restrict__ W,
                                                float* __restrict__ p2) {
    const int s = blockIdx.x, t = threadIdx.x;
    __shared__ float red[2][4][32];
    __shared__ float hs[4][32];

    {
        const int dd = t & 31, g = t >> 5;
        const int b = g & 3, half = g >> 2;
        const int d = s * 32 + dd;
        float part = 0.f;
#pragma unroll 8
        for (int k = 0; k < 32; ++k)
            part += p1[(((half * 32 + k) * 4) + b) * D + d];
        red[half][b][dd] = part;
    }
    __syncthreads();
    if (t < 128) {
        const int b = t >> 5, dd = t & 31;
        const float h = red[0][b][dd] + red[1][b][dd] + bias[s * 32 + dd];
        hs[b][dd] = fmaxf(h, 0.f);
    }
    __syncthreads();

    const vf4* W4 = (const vf4*)W;
    vf4 a0 = {0.f, 0.f, 0.f, 0.f}, a1 = a0, a2 = a0, a3 = a0;
#pragma unroll
    for (int i = 0; i < 32; ++i) {
        const vf4 w = W4[(s * 32 + i) * 256 + t];
        a0 += hs[0][i] * w;
        a1 += hs[1][i] * w;
        a2 += hs[2][i] * w;
        a3 += hs[3][i] * w;
    }
    vf4* P4 = (vf4*)p2;
    P4[(s * 4 + 0) * 256 + t] = a0;
    P4[(s * 4 + 1) * 256 + t] = a1;
    P4[(s * 4 + 2) * 256 + t] = a2;
    P4[(s * 4 + 3) * 256 + t] = a3;
}

// ---------------------------------------------------------------------------
// K3: reduce p2 (32 slices) + bias -> LayerNorm -> cosine pre-normalization.
// grid = 4 (one block per context row), block = 1024, thread owns column j.
// ---------------------------------------------------------------------------
__global__ __launch_bounds__(1024) void ln_cos_fused(const float* __restrict__ p2,
                                                     const float* __restrict__ bias,
                                                     const float* __restrict__ gamma,
                                                     const float* __restrict__ beta,
                                                     float* __restrict__ out) {
    const int b = blockIdx.x, j = threadIdx.x;
    const int lane = j & 63, wid = j >> 6;

    float h = 0.f;
#pragma unroll 8
    for (int sl = 0; sl < 32; ++sl) h += p2[(sl * 4 + b) * D + j];
    h += bias[j];

    float s = h, ss = h * h;
    __shared__ float rs[16], rss[16];
#pragma unroll
    for (int off = 32; off; off >>= 1) {
        s  += __shfl_xor(s, off, 64);
        ss += __shfl_xor(ss, off, 64);
    }
    if (lane == 0) { rs[wid] = s; rss[wid] = ss; }
    __syncthreads();
    s = 0.f; ss = 0.f;
#pragma unroll
    for (int k = 0; k < 16; ++k) { s += rs[k]; ss += rss[k]; }

    const float mu   = s * (1.f / D);
    const float var  = ss * (1.f / D) - mu * mu;
    const float rstd = rsqrtf(var + LN_EPS);
    const float y    = (h - mu) * rstd * gamma[j] + beta[j];

    float nsq = y * y;
    __shared__ float rn[16];
#pragma unroll
    for (int off = 32; off; off >>= 1) nsq += __shfl_xor(nsq, off, 64);
    __syncthreads();               // rs/rss reuse barrier not needed; rn fresh
    if (lane == 0) rn[wid] = nsq;
    __syncthreads();
    nsq = 0.f;
#pragma unroll
    for (int k = 0; k < 16; ++k) nsq += rn[k];

    const float inv = 1.f / fmaxf(sqrtf(nsq), COS_EPS);
    out[b * D + j] = y * inv;
}

// ---------------------------------------------------------------------------
// K4 (the streaming pass): one wave per episode row, 2 rows per iteration,
// 8 independent nontemporal float4 loads in flight, packed butterfly reduce.
// grid = 1024 blocks (co-resident), 4096 waves.
// ---------------------------------------------------------------------------
__global__ __launch_bounds__(256) void score_kernel(const float* __restrict__ ep,
                                                    const float* __restrict__ elapsed,
                                                    const float* __restrict__ ctxn,
                                                    float* __restrict__ out, int N) {
    const int lane = threadIdx.x & 63;
    const int wave = (blockIdx.x * 256 + threadIdx.x) >> 6;
    const int nw   = (gridDim.x * 256) >> 6;

    const vf4* c4 = (const vf4*)ctxn;
    vf4 c[4][4];
#pragma unroll
    for (int b = 0; b < 4; ++b)
#pragma unroll
        for (int k = 0; k < 4; ++k) c[b][k] = c4[b * 256 + k * 64 + lane];

    for (int n = wave; n < N; n += 2 * nw) {
        const int  n2    = n + nw;
        const bool have2 = n2 < N;

        const vf4* eA = (const vf4*)(ep + (size_t)n * D);
        const vf4* eB = (const vf4*)(ep + (size_t)n2 * D);

        vf4 ea[4], eb[4];
#pragma unroll
        for (int k = 0; k < 4; ++k) ea[k] = __builtin_nontemporal_load(eA + k * 64 + lane);
        if (have2) {
#pragma unroll
            for (int k = 0; k < 4; ++k) eb[k] = __builtin_nontemporal_load(eB + k * 64 + lane);
        } else {
#pragma unroll
            for (int k = 0; k < 4; ++k) eb[k] = vf4{0.f, 0.f, 0.f, 0.f};
        }

        float a[5]    = {0.f, 0.f, 0.f, 0.f, 0.f};
        float bacc[5] = {0.f, 0.f, 0.f, 0.f, 0.f};
#pragma unroll
        for (int k = 0; k < 4; ++k) {
#pragma unroll
            for (int i = 0; i < 4; ++i) {
                a[4]    = fmaf(ea[k][i], ea[k][i], a[4]);
                bacc[4] = fmaf(eb[k][i], eb[k][i], bacc[4]);
            }
#pragma unroll
            for (int b = 0; b < 4; ++b) {
#pragma unroll
                for (int i = 0; i < 4; ++i) {
                    a[b]    = fmaf(ea[k][i], c[b][k][i], a[b]);
                    bacc[b] = fmaf(eb[k][i], c[b][k][i], bacc[b]);
                }
            }
        }

        // level 32 merges the two rows; 5 more levels finish.
        float m[5];
#pragma unroll
        for (int i = 0; i < 5; ++i) {
            const float t = __shfl_xor(a[i], 32, 64);
            const float u = __shfl_xor(bacc[i], 32, 64);
            m[i] = (lane < 32) ? (a[i] + t) : (bacc[i] + u);
        }
#pragma unroll
        for (int off = 16; off; off >>= 1)
#pragma unroll
            for (int i = 0; i < 5; ++i) m[i] += __shfl_xor(m[i], off, 64);

        const int half = lane >> 5;
        const int rown = half ? n2 : n;
        if ((lane & 31) < 4 && (half == 0 || have2)) {
            const int   bsel = lane & 3;
            const float sim  = bsel == 0 ? m[0] : bsel == 1 ? m[1] : bsel == 2 ? m[2] : m[3];
            const float inv  = 1.f / fmaxf(sqrtf(m[4]), COS_EPS);
            const float w    = __expf(-TEMPORAL_DECAY * elapsed[rown]) + REL_TERM;
            const float sc   = sim * inv * w;
            out[(size_t)bsel * N + rown] = (sc > SIM_THRESHOLD) ? sc : 0.f;
        }
    }
}

// ---------------------------------------------------------------------------
extern "C" void kernel_launch(void* const* d_in, const int* in_sizes, int n_in,
                              void* d_out, int out_size, void* d_ws, size_t ws_size,
                              hipStream_t stream) {
    const float* ctx = (const float*)d_in[0];
    const float* ep  = (const float*)d_in[1];
    const float* el  = (const float*)d_in[2];
    const float* W1  = (const float*)d_in[3];
    const float* b1  = (const float*)d_in[4];
    const float* W2  = (const float*)d_in[5];
    const float* b2  = (const float*)d_in[6];
    const float* gg  = (const float*)d_in[7];
    const float* bb  = (const float*)d_in[8];
    float* out = (float*)d_out;
    const int N = in_sizes[2];

    float* p1 = (float*)d_ws;             // [64][4][1024]  = 1 MB
    float* p2 = p1 + 64 * 4 * D;          // [32][4][1024]  = 512 KB
    float* cn = p2 + 32 * 4 * D;          // [4][1024] normalized context

    g1_partial<<<64, 256, 0, stream>>>(ctx, W1, p1);
    g2_fused<<<32, 256, 0, stream>>>(p1, b1, W2, p2);
    ln_cos_fused<<<4, 1024, 0, stream>>>(p2, b2, gg, bb, cn);
    score_kernel<<<1024, 256, 0, stream>>>(ep, el, cn, out, N);
}